// Round 1
// baseline (277.057 us; speedup 1.0000x reference)
//
#include <hip/hip_runtime.h>

#define B_ 4
#define C_ 256
#define CQK 64
#define N_ 4096

typedef _Float16 f16;
typedef __attribute__((ext_vector_type(8))) _Float16 f16x8;
typedef __attribute__((ext_vector_type(4))) _Float16 f16x4;
typedef __attribute__((ext_vector_type(4))) float f32x4;

// ---------------- K_w: convert weights fp32 -> fp16 ----------------
__global__ __launch_bounds__(256) void cvt_weights(
    const float* __restrict__ wq, const float* __restrict__ wk,
    const float* __restrict__ wv, const float* __restrict__ wg,
    f16* __restrict__ owq, f16* __restrict__ owk,
    f16* __restrict__ owv, f16* __restrict__ owg) {
  int i = blockIdx.x * 256 + threadIdx.x;  // grid 256 blocks -> i < 65536
  if (i < CQK * C_) {
    owq[i] = (f16)wq[i];
    owk[i] = (f16)wk[i];
  }
  owv[i] = (f16)wv[i];
  owg[i] = (f16)wg[i];
}

// ---------------- K0: x[b][c][n] fp32 -> XT[b][n][c] fp16 ----------------
__global__ __launch_bounds__(256) void transpose_x(const float* __restrict__ x,
                                                   f16* __restrict__ xt) {
  // grid: (N/64, C/64, B)
  __shared__ float tile[64][65];
  int n0 = blockIdx.x * 64, c0 = blockIdx.y * 64, b = blockIdx.z;
  const float* xb = x + (size_t)b * C_ * N_;
  int lane = threadIdx.x & 63;  // n index
  int grp = threadIdx.x >> 6;   // 0..3
#pragma unroll
  for (int i = 0; i < 16; i++) {
    int c = grp * 16 + i;
    tile[lane][c] = xb[(size_t)(c0 + c) * N_ + n0 + lane];
  }
  __syncthreads();
  f16* xtb = xt + (size_t)b * N_ * C_;
#pragma unroll
  for (int i = 0; i < 16; i++) {
    int n = grp * 16 + i;
    xtb[(size_t)(n0 + n) * C_ + c0 + lane] = (f16)tile[n][lane];
  }
}

// ---------------- K1a: qT/kT[b][n][o] = (W x)^T + bias ----------------
__global__ __launch_bounds__(256) void proj_qk(const f16* __restrict__ Wf,
                                               const float* __restrict__ bias,
                                               const f16* __restrict__ xt,
                                               f16* __restrict__ outT) {
  // grid: (N/64, B). D = W[64x256] * X[256x64tile]; A=W rows, B-frags from XT.
  int n0 = blockIdx.x * 64;
  int b = blockIdx.y;
  int tid = threadIdx.x, lane = tid & 63, w = tid >> 6;
  int l15 = lane & 15, quad = lane >> 4;
  const f16* xtb = xt + ((size_t)b * N_ + n0) * C_;
  f32x4 acc[4];
#pragma unroll
  for (int nt = 0; nt < 4; nt++) acc[nt] = (f32x4){0.f, 0.f, 0.f, 0.f};
#pragma unroll
  for (int ks = 0; ks < 8; ks++) {
    int kbase = ks * 32 + quad * 8;
    f16x8 a = *(const f16x8*)(Wf + (16 * w + l15) * C_ + kbase);
#pragma unroll
    for (int nt = 0; nt < 4; nt++) {
      f16x8 bf = *(const f16x8*)(xtb + (16 * nt + l15) * C_ + kbase);
      acc[nt] = __builtin_amdgcn_mfma_f32_16x16x32_f16(a, bf, acc[nt], 0, 0, 0);
    }
  }
  // D[o][n]: row o = 16w + quad*4 + r, col n = n0 + 16nt + l15. Write outT[n][o].
  f16* ob = outT + (size_t)b * N_ * CQK;
  int o0 = 16 * w + quad * 4;
#pragma unroll
  for (int nt = 0; nt < 4; nt++) {
    int n = n0 + 16 * nt + l15;
    f16x4 vals;
#pragma unroll
    for (int r = 0; r < 4; r++) vals[r] = (f16)(acc[nt][r] + bias[o0 + r]);
    *(f16x4*)(ob + (size_t)n * CQK + o0) = vals;
  }
}

// ---------------- K1b: v[b][c][n] natural, via D = XT * Wv^T ----------------
__global__ __launch_bounds__(256) void proj_v(const f16* __restrict__ Wf,
                                              const float* __restrict__ bias,
                                              const f16* __restrict__ xt,
                                              f16* __restrict__ vout) {
  // grid: (N/64, C/64, B). A = XT rows (n), B cols = Wv rows (o).
  int n0 = blockIdx.x * 64, o0 = blockIdx.y * 64, b = blockIdx.z;
  int tid = threadIdx.x, lane = tid & 63, w = tid >> 6;
  int l15 = lane & 15, quad = lane >> 4;
  const f16* xtb = xt + ((size_t)b * N_ + n0) * C_;
  f32x4 acc[4];
#pragma unroll
  for (int ot = 0; ot < 4; ot++) acc[ot] = (f32x4){0.f, 0.f, 0.f, 0.f};
#pragma unroll
  for (int ks = 0; ks < 8; ks++) {
    int kbase = ks * 32 + quad * 8;
    f16x8 a = *(const f16x8*)(xtb + (16 * w + l15) * C_ + kbase);
#pragma unroll
    for (int ot = 0; ot < 4; ot++) {
      f16x8 bb = *(const f16x8*)(Wf + (size_t)(o0 + 16 * ot + l15) * C_ + kbase);
      acc[ot] = __builtin_amdgcn_mfma_f32_16x16x32_f16(a, bb, acc[ot], 0, 0, 0);
    }
  }
  // D[n][o]: row n = n0 + 16w + quad*4 + r, col o = o0 + 16ot + l15. Write v[o][n].
#pragma unroll
  for (int ot = 0; ot < 4; ot++) {
    int o = o0 + 16 * ot + l15;
    float bv = bias[o];
    int nl = n0 + 16 * w + quad * 4;
    f16x4 vals;
#pragma unroll
    for (int r = 0; r < 4; r++) vals[r] = (f16)(acc[ot][r] + bv);
    *(f16x4*)(vout + ((size_t)b * C_ + o) * N_ + nl) = vals;
  }
}

// ---------------- K2: fused attention ----------------
// OT[b][m][c] = (1/N) * sum_n v[c][n] * elu(sum_o q[o][n] k[o][m])
__global__ __launch_bounds__(256, 1) void attn(const f16* __restrict__ qt,
                                               const f16* __restrict__ kt,
                                               const f16* __restrict__ v,
                                               f16* __restrict__ outT) {
  // grid: (N/64 m-tiles, B); 4 waves.
  __shared__ f16 sPt[64][72];  // P^T: [m][n-local], +8 pad -> <=2-way conflicts
  int m0 = blockIdx.x * 64;
  int b = blockIdx.y;
  int tid = threadIdx.x, lane = tid & 63, w = tid >> 6;
  int l15 = lane & 15, quad = lane >> 4;
  const f16* qtb = qt + (size_t)b * N_ * CQK;
  const f16* ktb = kt + (size_t)b * N_ * CQK;
  const f16* vb = v + (size_t)b * C_ * N_;

  f32x4 oacc[4][4];  // [ct][mt]: rows c = 64w+16ct+quad*4+r, cols m = m0+16mt+l15
#pragma unroll
  for (int ct = 0; ct < 4; ct++)
#pragma unroll
    for (int mt = 0; mt < 4; mt++) oacc[ct][mt] = (f32x4){0.f, 0.f, 0.f, 0.f};

  // K fragments resident for the whole kernel (block's m-tile fixed)
  f16x8 kf[4][2];
#pragma unroll
  for (int mt = 0; mt < 4; mt++)
#pragma unroll
    for (int ks = 0; ks < 2; ks++)
      kf[mt][ks] = *(const f16x8*)(ktb + (size_t)(m0 + 16 * mt + l15) * CQK +
                                   ks * 32 + quad * 8);

  for (int n0 = 0; n0 < N_; n0 += 64) {
    // ---- S phase: S[n][m], rows n = n0+16w+..., cols m (4 tiles) ----
    f32x4 sacc[4];
#pragma unroll
    for (int mt = 0; mt < 4; mt++) sacc[mt] = (f32x4){0.f, 0.f, 0.f, 0.f};
#pragma unroll
    for (int ks = 0; ks < 2; ks++) {
      f16x8 a = *(const f16x8*)(qtb + (size_t)(n0 + 16 * w + l15) * CQK +
                                ks * 32 + quad * 8);
#pragma unroll
      for (int mt = 0; mt < 4; mt++)
        sacc[mt] = __builtin_amdgcn_mfma_f32_16x16x32_f16(a, kf[mt][ks], sacc[mt], 0, 0, 0);
    }
    __syncthreads();  // previous O-phase reads of sPt complete
    // elu, write P^T to LDS. D: col m = 16mt+l15, row n_local = 16w+quad*4+r
#pragma unroll
    for (int mt = 0; mt < 4; mt++) {
      f16x4 p;
#pragma unroll
      for (int r = 0; r < 4; r++) {
        float s = sacc[mt][r];
        p[r] = (f16)(s > 0.0f ? s : (__expf(s) - 1.0f));
      }
      *(f16x4*)(&sPt[16 * mt + l15][16 * w + quad * 4]) = p;
    }
    __syncthreads();  // P ready
    // ---- O phase: O[c][m] += V[c][n] * P[n][m] ----
#pragma unroll
    for (int ks = 0; ks < 2; ks++) {
      int nb = n0 + ks * 32 + quad * 8;
      f16x8 pa[4];
#pragma unroll
      for (int mt = 0; mt < 4; mt++)
        pa[mt] = *(const f16x8*)(&sPt[16 * mt + l15][ks * 32 + quad * 8]);
#pragma unroll
      for (int ct = 0; ct < 4; ct++) {
        f16x8 av = *(const f16x8*)(vb + (size_t)(64 * w + 16 * ct + l15) * N_ + nb);
#pragma unroll
        for (int mt = 0; mt < 4; mt++)
          oacc[ct][mt] = __builtin_amdgcn_mfma_f32_16x16x32_f16(av, pa[mt], oacc[ct][mt], 0, 0, 0);
      }
    }
  }
  // epilogue: OT[b][m][c] = oacc / N
  f16* ob = outT + (size_t)b * N_ * C_;
#pragma unroll
  for (int ct = 0; ct < 4; ct++) {
#pragma unroll
    for (int mt = 0; mt < 4; mt++) {
      int m = m0 + 16 * mt + l15;
      int c0l = 64 * w + 16 * ct + quad * 4;
      f16x4 vals;
#pragma unroll
      for (int r = 0; r < 4; r++)
        vals[r] = (f16)(oacc[ct][mt][r] * (1.0f / (float)N_));
      *(f16x4*)(ob + (size_t)m * C_ + c0l) = vals;
    }
  }
}

// ---------------- K3: out[b][o][m] = wg . O + bg ----------------
__global__ __launch_bounds__(256) void final_proj(const f16* __restrict__ Wf,
                                                  const float* __restrict__ bias,
                                                  const f16* __restrict__ ot,
                                                  float* __restrict__ out) {
  // grid: (N/64 m, C/64 o, B). A = wg rows (o), B-frags from OT[m][c].
  int m0 = blockIdx.x * 64, o0 = blockIdx.y * 64, b = blockIdx.z;
  int tid = threadIdx.x, lane = tid & 63, w = tid >> 6;
  int l15 = lane & 15, quad = lane >> 4;
  const f16* otb = ot + (size_t)b * N_ * C_;
  f32x4 acc[4];
#pragma unroll
  for (int mt = 0; mt < 4; mt++) acc[mt] = (f32x4){0.f, 0.f, 0.f, 0.f};
#pragma unroll
  for (int ks = 0; ks < 8; ks++) {
    int kbase = ks * 32 + quad * 8;
    f16x8 a = *(const f16x8*)(Wf + (size_t)(o0 + 16 * w + l15) * C_ + kbase);
#pragma unroll
    for (int mt = 0; mt < 4; mt++) {
      f16x8 bb = *(const f16x8*)(otb + (size_t)(m0 + 16 * mt + l15) * C_ + kbase);
      acc[mt] = __builtin_amdgcn_mfma_f32_16x16x32_f16(a, bb, acc[mt], 0, 0, 0);
    }
  }
  float* outb = out + (size_t)b * C_ * N_;
  int ol = o0 + 16 * w + quad * 4;
#pragma unroll
  for (int mt = 0; mt < 4; mt++) {
    int m = m0 + 16 * mt + l15;
#pragma unroll
    for (int r = 0; r < 4; r++)
      outb[(size_t)(ol + r) * N_ + m] = acc[mt][r] + bias[ol + r];
  }
}

extern "C" void kernel_launch(void* const* d_in, const int* in_sizes, int n_in,
                              void* d_out, int out_size, void* d_ws, size_t ws_size,
                              hipStream_t stream) {
  const float* x = (const float*)d_in[0];
  const float* wq = (const float*)d_in[1];
  const float* bq = (const float*)d_in[2];
  const float* wk = (const float*)d_in[3];
  const float* bk = (const float*)d_in[4];
  const float* wv = (const float*)d_in[5];
  const float* bv = (const float*)d_in[6];
  const float* wg = (const float*)d_in[7];
  const float* bg = (const float*)d_in[8];
  float* out = (float*)d_out;

  char* ws = (char*)d_ws;
  f16* XT = (f16*)ws; ws += (size_t)B_ * N_ * C_ * sizeof(f16);   // 8.4 MB
  f16* QT = (f16*)ws; ws += (size_t)B_ * N_ * CQK * sizeof(f16);  // 2.1 MB
  f16* KT = (f16*)ws; ws += (size_t)B_ * N_ * CQK * sizeof(f16);  // 2.1 MB
  f16* V  = (f16*)ws; ws += (size_t)B_ * C_ * N_ * sizeof(f16);   // 8.4 MB
  f16* OT = (f16*)ws; ws += (size_t)B_ * N_ * C_ * sizeof(f16);   // 8.4 MB
  f16* WQ = (f16*)ws; ws += (size_t)CQK * C_ * sizeof(f16);
  f16* WK = (f16*)ws; ws += (size_t)CQK * C_ * sizeof(f16);
  f16* WV = (f16*)ws; ws += (size_t)C_ * C_ * sizeof(f16);
  f16* WG = (f16*)ws; ws += (size_t)C_ * C_ * sizeof(f16);

  cvt_weights<<<dim3(256), 256, 0, stream>>>(wq, wk, wv, wg, WQ, WK, WV, WG);
  transpose_x<<<dim3(N_ / 64, C_ / 64, B_), 256, 0, stream>>>(x, XT);
  proj_qk<<<dim3(N_ / 64, B_), 256, 0, stream>>>(WQ, bq, XT, QT);
  proj_qk<<<dim3(N_ / 64, B_), 256, 0, stream>>>(WK, bk, XT, KT);
  proj_v<<<dim3(N_ / 64, C_ / 64, B_), 256, 0, stream>>>(WV, bv, XT, V);
  attn<<<dim3(N_ / 64, B_), 256, 0, stream>>>(QT, KT, V, OT);
  final_proj<<<dim3(N_ / 64, C_ / 64, B_), 256, 0, stream>>>(WG, bg, OT, out);
}

// Round 2
// 252.522 us; speedup vs baseline: 1.0972x; 1.0972x over previous
//
#include <hip/hip_runtime.h>

#define B_ 4
#define C_ 256
#define CQK 64
#define N_ 4096
#define SEG 2
#define SEGN (N_ / SEG)    // 2048
#define NB 128
#define ITERS (SEGN / NB)  // 16

typedef _Float16 f16;
typedef __attribute__((ext_vector_type(8))) _Float16 f16x8;
typedef __attribute__((ext_vector_type(4))) _Float16 f16x4;
typedef __attribute__((ext_vector_type(4))) float f32x4;

// ---------------- K_w: convert weights fp32 -> fp16 ----------------
__global__ __launch_bounds__(256) void cvt_weights(
    const float* __restrict__ wq, const float* __restrict__ wk,
    const float* __restrict__ wv, const float* __restrict__ wg,
    f16* __restrict__ owq, f16* __restrict__ owk,
    f16* __restrict__ owv, f16* __restrict__ owg) {
  int i = blockIdx.x * 256 + threadIdx.x;  // grid 256 blocks -> i < 65536
  if (i < CQK * C_) {
    owq[i] = (f16)wq[i];
    owk[i] = (f16)wk[i];
  }
  owv[i] = (f16)wv[i];
  owg[i] = (f16)wg[i];
}

// ---------------- K0: x[b][c][n] fp32 -> XT[b][n][c] fp16 ----------------
__global__ __launch_bounds__(256) void transpose_x(const float* __restrict__ x,
                                                   f16* __restrict__ xt) {
  // grid: (N/64, C/64, B)
  __shared__ float tile[64][65];
  int n0 = blockIdx.x * 64, c0 = blockIdx.y * 64, b = blockIdx.z;
  const float* xb = x + (size_t)b * C_ * N_;
  int lane = threadIdx.x & 63;  // n index
  int grp = threadIdx.x >> 6;   // 0..3
#pragma unroll
  for (int i = 0; i < 16; i++) {
    int c = grp * 16 + i;
    tile[lane][c] = xb[(size_t)(c0 + c) * N_ + n0 + lane];
  }
  __syncthreads();
  f16* xtb = xt + (size_t)b * N_ * C_;
#pragma unroll
  for (int i = 0; i < 16; i++) {
    int n = grp * 16 + i;
    xtb[(size_t)(n0 + n) * C_ + c0 + lane] = (f16)tile[n][lane];
  }
}

// ---------------- K1a: qT/kT[b][n][o] = (W x)^T + bias (Q and K merged) ----
__global__ __launch_bounds__(256) void proj_qk(const f16* __restrict__ WQf,
                                               const f16* __restrict__ WKf,
                                               const float* __restrict__ bq,
                                               const float* __restrict__ bk,
                                               const f16* __restrict__ xt,
                                               f16* __restrict__ QT,
                                               f16* __restrict__ KT) {
  // grid: (N/64, 2, B). D = W[64x256] * X[256x64tile]; A=W rows, B-frags from XT.
  int n0 = blockIdx.x * 64;
  int which = blockIdx.y;
  int b = blockIdx.z;
  const f16* Wf = which ? WKf : WQf;
  const float* bias = which ? bk : bq;
  f16* outT = which ? KT : QT;
  int tid = threadIdx.x, lane = tid & 63, w = tid >> 6;
  int l15 = lane & 15, quad = lane >> 4;
  const f16* xtb = xt + ((size_t)b * N_ + n0) * C_;
  f32x4 acc[4];
#pragma unroll
  for (int nt = 0; nt < 4; nt++) acc[nt] = (f32x4){0.f, 0.f, 0.f, 0.f};
#pragma unroll
  for (int ks = 0; ks < 8; ks++) {
    int kbase = ks * 32 + quad * 8;
    f16x8 a = *(const f16x8*)(Wf + (16 * w + l15) * C_ + kbase);
#pragma unroll
    for (int nt = 0; nt < 4; nt++) {
      f16x8 bf = *(const f16x8*)(xtb + (16 * nt + l15) * C_ + kbase);
      acc[nt] = __builtin_amdgcn_mfma_f32_16x16x32_f16(a, bf, acc[nt], 0, 0, 0);
    }
  }
  // D[o][n]: row o = 16w + quad*4 + r, col n = n0 + 16nt + l15. Write outT[n][o].
  f16* ob = outT + (size_t)b * N_ * CQK;
  int o0 = 16 * w + quad * 4;
#pragma unroll
  for (int nt = 0; nt < 4; nt++) {
    int n = n0 + 16 * nt + l15;
    f16x4 vals;
#pragma unroll
    for (int r = 0; r < 4; r++) vals[r] = (f16)(acc[nt][r] + bias[o0 + r]);
    *(f16x4*)(ob + (size_t)n * CQK + o0) = vals;
  }
}

// ---------------- K1b: v[b][c][n] natural, via D = XT * Wv^T ----------------
__global__ __launch_bounds__(256) void proj_v(const f16* __restrict__ Wf,
                                              const float* __restrict__ bias,
                                              const f16* __restrict__ xt,
                                              f16* __restrict__ vout) {
  // grid: (N/64, C/64, B). A = XT rows (n), B cols = Wv rows (o).
  int n0 = blockIdx.x * 64, o0 = blockIdx.y * 64, b = blockIdx.z;
  int tid = threadIdx.x, lane = tid & 63, w = tid >> 6;
  int l15 = lane & 15, quad = lane >> 4;
  const f16* xtb = xt + ((size_t)b * N_ + n0) * C_;
  f32x4 acc[4];
#pragma unroll
  for (int ot = 0; ot < 4; ot++) acc[ot] = (f32x4){0.f, 0.f, 0.f, 0.f};
#pragma unroll
  for (int ks = 0; ks < 8; ks++) {
    int kbase = ks * 32 + quad * 8;
    f16x8 a = *(const f16x8*)(xtb + (16 * w + l15) * C_ + kbase);
#pragma unroll
    for (int ot = 0; ot < 4; ot++) {
      f16x8 bb = *(const f16x8*)(Wf + (size_t)(o0 + 16 * ot + l15) * C_ + kbase);
      acc[ot] = __builtin_amdgcn_mfma_f32_16x16x32_f16(a, bb, acc[ot], 0, 0, 0);
    }
  }
  // D[n][o]: row n = n0 + 16w + quad*4 + r, col o = o0 + 16ot + l15. Write v[o][n].
#pragma unroll
  for (int ot = 0; ot < 4; ot++) {
    int o = o0 + 16 * ot + l15;
    float bv = bias[o];
    int nl = n0 + 16 * w + quad * 4;
    f16x4 vals;
#pragma unroll
    for (int r = 0; r < 4; r++) vals[r] = (f16)(acc[ot][r] + bv);
    *(f16x4*)(vout + ((size_t)b * C_ + o) * N_ + nl) = vals;
  }
}

// ---------------- K2: fused attention (n-split, NB=128, dbuf LDS) ----------
// OT[seg][b][m][c] = (1/N) * sum_{n in seg} v[c][n] * elu(sum_o q[o][n] k[o][m])
__global__ __launch_bounds__(256, 2) void attn(const f16* __restrict__ qt,
                                               const f16* __restrict__ kt,
                                               const f16* __restrict__ v,
                                               f16* __restrict__ oT) {
  // grid: (N/64 m-tiles, SEG, B); 4 waves.
  __shared__ f16 sPt[2][64][136];  // P^T dbuf: [m][n-local]; 2x17KB = 34.8KB
  int m0 = blockIdx.x * 64;
  int seg = blockIdx.y;
  int b = blockIdx.z;
  int tid = threadIdx.x, lane = tid & 63, w = tid >> 6;
  int l15 = lane & 15, quad = lane >> 4;
  const f16* qtb = qt + (size_t)b * N_ * CQK;
  const f16* ktb = kt + (size_t)b * N_ * CQK;
  const f16* vb = v + (size_t)b * C_ * N_;

  f32x4 oacc[4][4];  // [ct][mt]: rows c = 64w+16ct+quad*4+r, cols m = m0+16mt+l15
#pragma unroll
  for (int ct = 0; ct < 4; ct++)
#pragma unroll
    for (int mt = 0; mt < 4; mt++) oacc[ct][mt] = (f32x4){0.f, 0.f, 0.f, 0.f};

  // K fragments resident for the whole kernel (block's m-tile fixed)
  f16x8 kf[4][2];
#pragma unroll
  for (int mt = 0; mt < 4; mt++)
#pragma unroll
    for (int ks = 0; ks < 2; ks++)
      kf[mt][ks] = *(const f16x8*)(ktb + (size_t)(m0 + 16 * mt + l15) * CQK +
                                   ks * 32 + quad * 8);

  for (int it = 0; it < ITERS; it++) {
    int n0 = seg * SEGN + it * NB;
    // ---- S phase: S[n][m], 128 n rows (32/wave), 64 m cols ----
    f32x4 sacc[2][4];
#pragma unroll
    for (int nt = 0; nt < 2; nt++)
#pragma unroll
      for (int mt = 0; mt < 4; mt++) sacc[nt][mt] = (f32x4){0.f, 0.f, 0.f, 0.f};
#pragma unroll
    for (int nt = 0; nt < 2; nt++) {
#pragma unroll
      for (int ks = 0; ks < 2; ks++) {
        f16x8 a = *(const f16x8*)(qtb +
                                  (size_t)(n0 + 32 * w + 16 * nt + l15) * CQK +
                                  ks * 32 + quad * 8);
#pragma unroll
        for (int mt = 0; mt < 4; mt++)
          sacc[nt][mt] =
              __builtin_amdgcn_mfma_f32_16x16x32_f16(a, kf[mt][ks], sacc[nt][mt], 0, 0, 0);
      }
    }
    // elu, write P^T to LDS dbuf. D: col m = 16mt+l15, row n = 32w+16nt+4quad+r
    f16(*buf)[136] = sPt[it & 1];
#pragma unroll
    for (int nt = 0; nt < 2; nt++) {
#pragma unroll
      for (int mt = 0; mt < 4; mt++) {
        f16x4 p;
#pragma unroll
        for (int r = 0; r < 4; r++) {
          float s = sacc[nt][mt][r];
          p[r] = (f16)(s > 0.0f ? s : (__expf(s) - 1.0f));
        }
        *(f16x4*)(&buf[16 * mt + l15][32 * w + 16 * nt + 4 * quad]) = p;
      }
    }
    __syncthreads();  // P ready; prev buffer's readers already passed prior barrier
    // ---- O phase: O[c][m] += V[c][n] * P[n][m] ----
#pragma unroll
    for (int ks = 0; ks < 4; ks++) {
      f16x8 pa[4];
#pragma unroll
      for (int mt = 0; mt < 4; mt++)
        pa[mt] = *(const f16x8*)(&buf[16 * mt + l15][ks * 32 + quad * 8]);
#pragma unroll
      for (int ct = 0; ct < 4; ct++) {
        f16x8 av = *(const f16x8*)(vb + (size_t)(64 * w + 16 * ct + l15) * N_ +
                                   n0 + ks * 32 + quad * 8);
#pragma unroll
        for (int mt = 0; mt < 4; mt++)
          oacc[ct][mt] =
              __builtin_amdgcn_mfma_f32_16x16x32_f16(av, pa[mt], oacc[ct][mt], 0, 0, 0);
      }
    }
  }
  // epilogue: OT[seg][b][m][c] = oacc / N (f16 partial; final_proj sums segs)
  f16* ob = oT + ((size_t)seg * B_ + b) * N_ * C_;
#pragma unroll
  for (int ct = 0; ct < 4; ct++) {
#pragma unroll
    for (int mt = 0; mt < 4; mt++) {
      int m = m0 + 16 * mt + l15;
      int c0l = 64 * w + 16 * ct + 4 * quad;
      f16x4 vals;
#pragma unroll
      for (int r = 0; r < 4; r++)
        vals[r] = (f16)(oacc[ct][mt][r] * (1.0f / (float)N_));
      *(f16x4*)(ob + (size_t)m * C_ + c0l) = vals;
    }
  }
}

// ---------------- K3: out[b][o][m] = wg . (OT0+OT1) + bg ----------------
__global__ __launch_bounds__(256) void final_proj(const f16* __restrict__ Wf,
                                                  const float* __restrict__ bias,
                                                  const f16* __restrict__ ot,
                                                  float* __restrict__ out) {
  // grid: (N/64 m, C/64 o, B). A = wg rows (o), B-frags from OT[m][c] (2 segs).
  int m0 = blockIdx.x * 64, o0 = blockIdx.y * 64, b = blockIdx.z;
  int tid = threadIdx.x, lane = tid & 63, w = tid >> 6;
  int l15 = lane & 15, quad = lane >> 4;
  const f16* otb0 = ot + (size_t)b * N_ * C_;
  const f16* otb1 = ot + ((size_t)B_ + b) * N_ * C_;
  f32x4 acc[4];
#pragma unroll
  for (int mt = 0; mt < 4; mt++) acc[mt] = (f32x4){0.f, 0.f, 0.f, 0.f};
#pragma unroll
  for (int ks = 0; ks < 8; ks++) {
    int kbase = ks * 32 + quad * 8;
    f16x8 a = *(const f16x8*)(Wf + (size_t)(o0 + 16 * w + l15) * C_ + kbase);
#pragma unroll
    for (int mt = 0; mt < 4; mt++) {
      size_t off = (size_t)(m0 + 16 * mt + l15) * C_ + kbase;
      f16x8 b0 = *(const f16x8*)(otb0 + off);
      f16x8 b1 = *(const f16x8*)(otb1 + off);
      f16x8 bb = b0 + b1;
      acc[mt] = __builtin_amdgcn_mfma_f32_16x16x32_f16(a, bb, acc[mt], 0, 0, 0);
    }
  }
  float* outb = out + (size_t)b * C_ * N_;
  int ol = o0 + 16 * w + quad * 4;
#pragma unroll
  for (int mt = 0; mt < 4; mt++) {
    int m = m0 + 16 * mt + l15;
#pragma unroll
    for (int r = 0; r < 4; r++)
      outb[(size_t)(ol + r) * N_ + m] = acc[mt][r] + bias[ol + r];
  }
}

extern "C" void kernel_launch(void* const* d_in, const int* in_sizes, int n_in,
                              void* d_out, int out_size, void* d_ws, size_t ws_size,
                              hipStream_t stream) {
  const float* x = (const float*)d_in[0];
  const float* wq = (const float*)d_in[1];
  const float* bq = (const float*)d_in[2];
  const float* wk = (const float*)d_in[3];
  const float* bk = (const float*)d_in[4];
  const float* wv = (const float*)d_in[5];
  const float* bv = (const float*)d_in[6];
  const float* wg = (const float*)d_in[7];
  const float* bg = (const float*)d_in[8];
  float* out = (float*)d_out;

  char* ws = (char*)d_ws;
  // OT: [SEG][B][N][C] f16, 16.8 MB. Seg0 aliases XT (XT dead before attn).
  f16* OT = (f16*)ws;
  f16* XT = (f16*)ws;
  ws += (size_t)SEG * B_ * N_ * C_ * sizeof(f16);                 // 16.8 MB
  f16* QT = (f16*)ws; ws += (size_t)B_ * N_ * CQK * sizeof(f16);  // 2.1 MB
  f16* KT = (f16*)ws; ws += (size_t)B_ * N_ * CQK * sizeof(f16);  // 2.1 MB
  f16* V  = (f16*)ws; ws += (size_t)B_ * C_ * N_ * sizeof(f16);   // 8.4 MB
  f16* WQ = (f16*)ws; ws += (size_t)CQK * C_ * sizeof(f16);
  f16* WK = (f16*)ws; ws += (size_t)CQK * C_ * sizeof(f16);
  f16* WV = (f16*)ws; ws += (size_t)C_ * C_ * sizeof(f16);
  f16* WG = (f16*)ws; ws += (size_t)C_ * C_ * sizeof(f16);

  cvt_weights<<<dim3(256), 256, 0, stream>>>(wq, wk, wv, wg, WQ, WK, WV, WG);
  transpose_x<<<dim3(N_ / 64, C_ / 64, B_), 256, 0, stream>>>(x, XT);
  proj_qk<<<dim3(N_ / 64, 2, B_), 256, 0, stream>>>(WQ, WK, bq, bk, XT, QT, KT);
  proj_v<<<dim3(N_ / 64, C_ / 64, B_), 256, 0, stream>>>(WV, bv, XT, V);
  attn<<<dim3(N_ / 64, SEG, B_), 256, 0, stream>>>(QT, KT, V, OT);
  final_proj<<<dim3(N_ / 64, C_ / 64, B_), 256, 0, stream>>>(WG, bg, OT, out);
}

// Round 3
// 232.041 us; speedup vs baseline: 1.1940x; 1.0883x over previous
//
#include <hip/hip_runtime.h>

#define B_ 4
#define C_ 256
#define CQK 64
#define N_ 4096
#define SEG 2
#define SEGN (N_ / SEG)    // 2048
#define NB 128
#define ITERS (SEGN / NB)  // 16

typedef _Float16 f16;
typedef __attribute__((ext_vector_type(8))) _Float16 f16x8;
typedef __attribute__((ext_vector_type(4))) _Float16 f16x4;
typedef __attribute__((ext_vector_type(4))) float f32x4;

// ---------------- K0: transpose x + convert weights (merged) ----------------
__global__ __launch_bounds__(256) void prep(
    const float* __restrict__ x, const float* __restrict__ wq,
    const float* __restrict__ wk, const float* __restrict__ wv,
    const float* __restrict__ wg, f16* __restrict__ xt, f16* __restrict__ WQ,
    f16* __restrict__ WK, f16* __restrict__ WV, f16* __restrict__ WG) {
  // grid: (68, 4, 4). x<64: transpose tile (n0=x*64, c0=y*64, b=z).
  //                   x>=64: weight fp32->fp16 (64 blocks, 16384 threads).
  __shared__ float tile[64][65];
  if (blockIdx.x < 64) {
    int n0 = blockIdx.x * 64, c0 = blockIdx.y * 64, b = blockIdx.z;
    const float* xb = x + (size_t)b * C_ * N_;
    int lane = threadIdx.x & 63;
    int grp = threadIdx.x >> 6;
#pragma unroll
    for (int i = 0; i < 16; i++) {
      int c = grp * 16 + i;
      tile[lane][c] = xb[(size_t)(c0 + c) * N_ + n0 + lane];
    }
    __syncthreads();
    f16* xtb = xt + (size_t)b * N_ * C_;
#pragma unroll
    for (int i = 0; i < 16; i++) {
      int n = grp * 16 + i;
      xtb[(size_t)(n0 + n) * C_ + c0 + lane] = (f16)tile[n][lane];
    }
  } else {
    int wid = (((blockIdx.x - 64) * 16) + blockIdx.z * 4 + blockIdx.y) * 256 +
              threadIdx.x;  // 0..16383
    for (int i = wid; i < 163840; i += 16384) {
      if (i < 16384) WQ[i] = (f16)wq[i];
      else if (i < 32768) WK[i - 16384] = (f16)wk[i - 16384];
      else if (i < 98304) WV[i - 32768] = (f16)wv[i - 32768];
      else WG[i - 98304] = (f16)wg[i - 98304];
    }
  }
}

// ---------------- K1: Q/K/V projections (merged) ----------------
__global__ __launch_bounds__(256) void proj_all(
    const f16* __restrict__ WQf, const f16* __restrict__ WKf,
    const f16* __restrict__ WVf, const float* __restrict__ bq,
    const float* __restrict__ bk, const float* __restrict__ bv,
    const f16* __restrict__ xt, f16* __restrict__ QT, f16* __restrict__ KT,
    f16* __restrict__ vout) {
  // grid: (N/64, 6, B). y<2 -> q/k path; y>=2 -> v path with o0=(y-2)*64.
  int n0 = blockIdx.x * 64;
  int y = blockIdx.y;
  int b = blockIdx.z;
  int tid = threadIdx.x, lane = tid & 63, w = tid >> 6;
  int l15 = lane & 15, quad = lane >> 4;
  const f16* xtb = xt + ((size_t)b * N_ + n0) * C_;
  if (y < 2) {
    const f16* Wf = y ? WKf : WQf;
    const float* bias = y ? bk : bq;
    f16* outT = y ? KT : QT;
    f32x4 acc[4];
#pragma unroll
    for (int nt = 0; nt < 4; nt++) acc[nt] = (f32x4){0.f, 0.f, 0.f, 0.f};
#pragma unroll
    for (int ks = 0; ks < 8; ks++) {
      int kbase = ks * 32 + quad * 8;
      f16x8 a = *(const f16x8*)(Wf + (16 * w + l15) * C_ + kbase);
#pragma unroll
      for (int nt = 0; nt < 4; nt++) {
        f16x8 bf = *(const f16x8*)(xtb + (16 * nt + l15) * C_ + kbase);
        acc[nt] = __builtin_amdgcn_mfma_f32_16x16x32_f16(a, bf, acc[nt], 0, 0, 0);
      }
    }
    // D[o][n]: row o = 16w+quad*4+r, col n = n0+16nt+l15. Write outT[n][o].
    f16* ob = outT + (size_t)b * N_ * CQK;
    int o0 = 16 * w + quad * 4;
#pragma unroll
    for (int nt = 0; nt < 4; nt++) {
      int n = n0 + 16 * nt + l15;
      f16x4 vals;
#pragma unroll
      for (int r = 0; r < 4; r++) vals[r] = (f16)(acc[nt][r] + bias[o0 + r]);
      *(f16x4*)(ob + (size_t)n * CQK + o0) = vals;
    }
  } else {
    int o0 = (y - 2) * 64;
    f32x4 acc[4];
#pragma unroll
    for (int ot = 0; ot < 4; ot++) acc[ot] = (f32x4){0.f, 0.f, 0.f, 0.f};
#pragma unroll
    for (int ks = 0; ks < 8; ks++) {
      int kbase = ks * 32 + quad * 8;
      f16x8 a = *(const f16x8*)(xtb + (16 * w + l15) * C_ + kbase);
#pragma unroll
      for (int ot = 0; ot < 4; ot++) {
        f16x8 bb = *(const f16x8*)(WVf + (size_t)(o0 + 16 * ot + l15) * C_ + kbase);
        acc[ot] = __builtin_amdgcn_mfma_f32_16x16x32_f16(a, bb, acc[ot], 0, 0, 0);
      }
    }
    // D[n][o]: row n = n0+16w+quad*4+r, col o = o0+16ot+l15. Write v[o][n].
#pragma unroll
    for (int ot = 0; ot < 4; ot++) {
      int o = o0 + 16 * ot + l15;
      float bvv = bv[o];
      int nl = n0 + 16 * w + quad * 4;
      f16x4 vals;
#pragma unroll
      for (int r = 0; r < 4; r++) vals[r] = (f16)(acc[ot][r] + bvv);
      *(f16x4*)(vout + ((size_t)b * C_ + o) * N_ + nl) = vals;
    }
  }
}

// ---------------- K2: fused attention (register-prefetch pipeline) ----------
// OT[seg][b][m][c] = (1/N) * sum_{n in seg} v[c][n] * elu(sum_o q[o][n] k[o][m])
__global__ __launch_bounds__(256, 2) void attn(const f16* __restrict__ qt,
                                               const f16* __restrict__ kt,
                                               const f16* __restrict__ v,
                                               f16* __restrict__ oT) {
  // grid: (N/64 m-tiles, SEG, B); 4 waves.
  __shared__ f16 sPt[2][64][136];  // P^T dbuf
  int m0 = blockIdx.x * 64;
  int seg = blockIdx.y;
  int b = blockIdx.z;
  int tid = threadIdx.x, lane = tid & 63, w = tid >> 6;
  int l15 = lane & 15, quad = lane >> 4;
  const f16* qtb = qt + (size_t)b * N_ * CQK;
  const f16* ktb = kt + (size_t)b * N_ * CQK;
  const f16* vb = v + (size_t)b * C_ * N_;

  f32x4 oacc[4][4];  // [ct][mt] -> AGPRs
#pragma unroll
  for (int ct = 0; ct < 4; ct++)
#pragma unroll
    for (int mt = 0; mt < 4; mt++) oacc[ct][mt] = (f32x4){0.f, 0.f, 0.f, 0.f};

  // K fragments resident for the whole kernel
  f16x8 kf[4][2];
#pragma unroll
  for (int mt = 0; mt < 4; mt++)
#pragma unroll
    for (int ks = 0; ks < 2; ks++)
      kf[mt][ks] = *(const f16x8*)(ktb + (size_t)(m0 + 16 * mt + l15) * CQK +
                                   ks * 32 + quad * 8);

  // prefetch Q[it=0]
  f16x8 qf[2][2];
  {
    int nq = seg * SEGN;
#pragma unroll
    for (int nt = 0; nt < 2; nt++)
#pragma unroll
      for (int ks = 0; ks < 2; ks++)
        qf[nt][ks] = *(const f16x8*)(qtb + (size_t)(nq + 32 * w + 16 * nt + l15) * CQK +
                                     ks * 32 + quad * 8);
  }

  for (int it = 0; it < ITERS; it++) {
    int n0 = seg * SEGN + it * NB;
    // issue V[it] first half (ks 0,1) now; consumed after the barrier
    f16x8 vfA[2][4];
#pragma unroll
    for (int ks = 0; ks < 2; ks++)
#pragma unroll
      for (int ct = 0; ct < 4; ct++)
        vfA[ks][ct] = *(const f16x8*)(vb + (size_t)(64 * w + 16 * ct + l15) * N_ +
                                      n0 + ks * 32 + quad * 8);

    // ---- S phase: uses prefetched qf ----
    f16(*buf)[136] = sPt[it & 1];
#pragma unroll
    for (int nt = 0; nt < 2; nt++) {
      f32x4 sacc[4];
#pragma unroll
      for (int mt = 0; mt < 4; mt++) sacc[mt] = (f32x4){0.f, 0.f, 0.f, 0.f};
#pragma unroll
      for (int ks = 0; ks < 2; ks++)
#pragma unroll
        for (int mt = 0; mt < 4; mt++)
          sacc[mt] = __builtin_amdgcn_mfma_f32_16x16x32_f16(qf[nt][ks], kf[mt][ks],
                                                            sacc[mt], 0, 0, 0);
      // elu, write P^T. D: col m = 16mt+l15, row n = 32w+16nt+4quad+r
#pragma unroll
      for (int mt = 0; mt < 4; mt++) {
        f16x4 p;
#pragma unroll
        for (int r = 0; r < 4; r++) {
          float s = sacc[mt][r];
          p[r] = (f16)(s > 0.0f ? s : (__expf(s) - 1.0f));
        }
        *(f16x4*)(&buf[16 * mt + l15][32 * w + 16 * nt + 4 * quad]) = p;
      }
    }
    __syncthreads();  // vmcnt drain: vfA issued ~16 MFMA + elu ago -> done

    // ---- O phase ----
    f16x8 vfB[2][4];
    f16x8 pa[4];
    // ks0 LDS reads + issue V second half (consumed 32 MFMAs later)
#pragma unroll
    for (int mt = 0; mt < 4; mt++)
      pa[mt] = *(const f16x8*)(&buf[16 * mt + l15][quad * 8]);
#pragma unroll
    for (int ks = 0; ks < 2; ks++)
#pragma unroll
      for (int ct = 0; ct < 4; ct++)
        vfB[ks][ct] = *(const f16x8*)(vb + (size_t)(64 * w + 16 * ct + l15) * N_ +
                                      n0 + 64 + ks * 32 + quad * 8);
#pragma unroll
    for (int ct = 0; ct < 4; ct++)
#pragma unroll
      for (int mt = 0; mt < 4; mt++)
        oacc[ct][mt] = __builtin_amdgcn_mfma_f32_16x16x32_f16(vfA[0][ct], pa[mt],
                                                              oacc[ct][mt], 0, 0, 0);
    // prefetch Q[it+1] (consumed next S-phase)
    if (it + 1 < ITERS) {
      int nq = n0 + NB;
#pragma unroll
      for (int nt = 0; nt < 2; nt++)
#pragma unroll
        for (int ks = 0; ks < 2; ks++)
          qf[nt][ks] = *(const f16x8*)(qtb + (size_t)(nq + 32 * w + 16 * nt + l15) * CQK +
                                       ks * 32 + quad * 8);
    }
    // ks1
#pragma unroll
    for (int mt = 0; mt < 4; mt++)
      pa[mt] = *(const f16x8*)(&buf[16 * mt + l15][32 + quad * 8]);
#pragma unroll
    for (int ct = 0; ct < 4; ct++)
#pragma unroll
      for (int mt = 0; mt < 4; mt++)
        oacc[ct][mt] = __builtin_amdgcn_mfma_f32_16x16x32_f16(vfA[1][ct], pa[mt],
                                                              oacc[ct][mt], 0, 0, 0);
    // ks2
#pragma unroll
    for (int mt = 0; mt < 4; mt++)
      pa[mt] = *(const f16x8*)(&buf[16 * mt + l15][64 + quad * 8]);
#pragma unroll
    for (int ct = 0; ct < 4; ct++)
#pragma unroll
      for (int mt = 0; mt < 4; mt++)
        oacc[ct][mt] = __builtin_amdgcn_mfma_f32_16x16x32_f16(vfB[0][ct], pa[mt],
                                                              oacc[ct][mt], 0, 0, 0);
    // ks3
#pragma unroll
    for (int mt = 0; mt < 4; mt++)
      pa[mt] = *(const f16x8*)(&buf[16 * mt + l15][96 + quad * 8]);
#pragma unroll
    for (int ct = 0; ct < 4; ct++)
#pragma unroll
      for (int mt = 0; mt < 4; mt++)
        oacc[ct][mt] = __builtin_amdgcn_mfma_f32_16x16x32_f16(vfB[1][ct], pa[mt],
                                                              oacc[ct][mt], 0, 0, 0);
  }

  // epilogue: OT[seg][b][m][c] = oacc / N (f16 partial; final_proj sums segs)
  f16* ob = oT + ((size_t)seg * B_ + b) * N_ * C_;
#pragma unroll
  for (int ct = 0; ct < 4; ct++) {
#pragma unroll
    for (int mt = 0; mt < 4; mt++) {
      int m = m0 + 16 * mt + l15;
      int c0l = 64 * w + 16 * ct + 4 * quad;
      f16x4 vals;
#pragma unroll
      for (int r = 0; r < 4; r++)
        vals[r] = (f16)(oacc[ct][mt][r] * (1.0f / (float)N_));
      *(f16x4*)(ob + (size_t)m * C_ + c0l) = vals;
    }
  }
}

// ---------------- K3: out[b][o][m] = wg . (OT0+OT1) + bg ----------------
__global__ __launch_bounds__(256) void final_proj(const f16* __restrict__ Wf,
                                                  const float* __restrict__ bias,
                                                  const f16* __restrict__ ot,
                                                  float* __restrict__ out) {
  // grid: (N/64 m, C/64 o, B). A = wg rows (o), B-frags from OT[m][c] (2 segs).
  int m0 = blockIdx.x * 64, o0 = blockIdx.y * 64, b = blockIdx.z;
  int tid = threadIdx.x, lane = tid & 63, w = tid >> 6;
  int l15 = lane & 15, quad = lane >> 4;
  const f16* otb0 = ot + (size_t)b * N_ * C_;
  const f16* otb1 = ot + ((size_t)B_ + b) * N_ * C_;
  f32x4 acc[4];
#pragma unroll
  for (int mt = 0; mt < 4; mt++) acc[mt] = (f32x4){0.f, 0.f, 0.f, 0.f};
#pragma unroll
  for (int ks = 0; ks < 8; ks++) {
    int kbase = ks * 32 + quad * 8;
    f16x8 a = *(const f16x8*)(Wf + (size_t)(o0 + 16 * w + l15) * C_ + kbase);
#pragma unroll
    for (int mt = 0; mt < 4; mt++) {
      size_t off = (size_t)(m0 + 16 * mt + l15) * C_ + kbase;
      f16x8 b0 = *(const f16x8*)(otb0 + off);
      f16x8 b1 = *(const f16x8*)(otb1 + off);
      f16x8 bb = b0 + b1;
      acc[mt] = __builtin_amdgcn_mfma_f32_16x16x32_f16(a, bb, acc[mt], 0, 0, 0);
    }
  }
  float* outb = out + (size_t)b * C_ * N_;
  int ol = o0 + 16 * w + quad * 4;
#pragma unroll
  for (int mt = 0; mt < 4; mt++) {
    int m = m0 + 16 * mt + l15;
#pragma unroll
    for (int r = 0; r < 4; r++)
      outb[(size_t)(ol + r) * N_ + m] = acc[mt][r] + bias[ol + r];
  }
}

extern "C" void kernel_launch(void* const* d_in, const int* in_sizes, int n_in,
                              void* d_out, int out_size, void* d_ws, size_t ws_size,
                              hipStream_t stream) {
  const float* x = (const float*)d_in[0];
  const float* wq = (const float*)d_in[1];
  const float* bq = (const float*)d_in[2];
  const float* wk = (const float*)d_in[3];
  const float* bk = (const float*)d_in[4];
  const float* wv = (const float*)d_in[5];
  const float* bv = (const float*)d_in[6];
  const float* wg = (const float*)d_in[7];
  const float* bg = (const float*)d_in[8];
  float* out = (float*)d_out;

  char* ws = (char*)d_ws;
  // OT: [SEG][B][N][C] f16, 16.8 MB. Seg0 aliases XT (XT dead before attn).
  f16* OT = (f16*)ws;
  f16* XT = (f16*)ws;
  ws += (size_t)SEG * B_ * N_ * C_ * sizeof(f16);                 // 16.8 MB
  f16* QT = (f16*)ws; ws += (size_t)B_ * N_ * CQK * sizeof(f16);  // 2.1 MB
  f16* KT = (f16*)ws; ws += (size_t)B_ * N_ * CQK * sizeof(f16);  // 2.1 MB
  f16* V  = (f16*)ws; ws += (size_t)B_ * C_ * N_ * sizeof(f16);   // 8.4 MB
  f16* WQ = (f16*)ws; ws += (size_t)CQK * C_ * sizeof(f16);
  f16* WK = (f16*)ws; ws += (size_t)CQK * C_ * sizeof(f16);
  f16* WV = (f16*)ws; ws += (size_t)C_ * C_ * sizeof(f16);
  f16* WG = (f16*)ws; ws += (size_t)C_ * C_ * sizeof(f16);

  prep<<<dim3(68, 4, 4), 256, 0, stream>>>(x, wq, wk, wv, wg, XT, WQ, WK, WV, WG);
  proj_all<<<dim3(N_ / 64, 6, B_), 256, 0, stream>>>(WQ, WK, WV, bq, bk, bv, XT,
                                                     QT, KT, V);
  attn<<<dim3(N_ / 64, SEG, B_), 256, 0, stream>>>(QT, KT, V, OT);
  final_proj<<<dim3(N_ / 64, C_ / 64, B_), 256, 0, stream>>>(WG, bg, OT, out);
}

// Round 5
// 172.769 us; speedup vs baseline: 1.6036x; 1.3431x over previous
//
#include <hip/hip_runtime.h>

#define B_ 4
#define C_ 256
#define CQK 64
#define N_ 4096
#define SEG 2
#define SEGN (N_ / SEG)    // 2048
#define NB 128
#define ITERS (SEGN / NB)  // 16
#define TS 512             // elements per 16x32 fragment tile (1 KB)

typedef _Float16 f16;
typedef __attribute__((ext_vector_type(8))) _Float16 f16x8;
typedef __attribute__((ext_vector_type(4))) _Float16 f16x4;
typedef __attribute__((ext_vector_type(4))) float f32x4;

// All MFMA operands live in fragment-tiled layout: matrix [R][K] stored as
// [R/16][K/32] tiles of [16][32] f16. A wave's fragment load (lane l15 = row,
// quad*8 = k-offset, 16 B/lane) covers one contiguous 1 KB tile -> coalesced.
#define TILE_OFF(l15, quad) ((l15) * 32 + (quad) * 8)

// ---------------- K0: tile-transpose x + tile-convert weights ----------------
__global__ __launch_bounds__(256) void prep(
    const float* __restrict__ x, const float* __restrict__ wq,
    const float* __restrict__ wk, const float* __restrict__ wv,
    const float* __restrict__ wg, f16* __restrict__ xtt, f16* __restrict__ WQt,
    f16* __restrict__ WKt, f16* __restrict__ WVt, f16* __restrict__ WGt) {
  // grid: (68, 4, 4). x<64: transpose tile (n0=x*64, c0=y*64, b=z).
  //                   x>=64: weights fp32 -> f16 tiles.
  __shared__ float tile[64][65];
  if (blockIdx.x < 64) {
    int n0 = blockIdx.x * 64, c0 = blockIdx.y * 64, b = blockIdx.z;
    const float* xb = x + (size_t)b * C_ * N_;
    int lane = threadIdx.x & 63;
    int grp = threadIdx.x >> 6;
#pragma unroll
    for (int i = 0; i < 16; i++) {
      int c = grp * 16 + i;
      tile[lane][c] = xb[(size_t)(c0 + c) * N_ + n0 + lane];
    }
    __syncthreads();
    // XTt: B-tiles [n/16][8][16][32] per batch
    f16* xtb = xtt + (size_t)b * N_ * C_;
    int ti = threadIdx.x >> 6;        // n-tile within this 64-row block
    int l15 = threadIdx.x & 15;       // row within tile
    int qq = (threadIdx.x >> 4) & 3;  // 16-col quarter
    int nl = ti * 16 + l15;
    size_t tb = ((size_t)((n0 >> 4) + ti) * 8 + (c0 >> 5) + (qq >> 1)) * TS;
    f16* dst = xtb + tb + l15 * 32 + (qq & 1) * 16;
    f16x8 v0, v1;
#pragma unroll
    for (int j = 0; j < 8; j++) v0[j] = (f16)tile[nl][qq * 16 + j];
#pragma unroll
    for (int j = 0; j < 8; j++) v1[j] = (f16)tile[nl][qq * 16 + 8 + j];
    *(f16x8*)dst = v0;
    *(f16x8*)(dst + 8) = v1;
  } else {
    // 16384 threads convert 163840 weight elements in 8-el chunks (20480).
    int wid = (((blockIdx.x - 64) * 16) + blockIdx.z * 4 + blockIdx.y) * 256 +
              threadIdx.x;
    for (int chunk = wid; chunk < 20480; chunk += 16384) {
      const float* src;
      f16* dst;
      int lo;
      if (chunk < 2048) { src = wq; dst = WQt; lo = chunk * 8; }
      else if (chunk < 4096) { src = wk; dst = WKt; lo = (chunk - 2048) * 8; }
      else if (chunk < 12288) { src = wv; dst = WVt; lo = (chunk - 4096) * 8; }
      else { src = wg; dst = WGt; lo = (chunk - 12288) * 8; }
      int o = lo >> 8, k = lo & 255;
      f16x8 v;
#pragma unroll
      for (int j = 0; j < 8; j++) v[j] = (f16)src[lo + j];
      *(f16x8*)(dst + ((size_t)(o >> 4) * 8 + (k >> 5)) * TS + (o & 15) * 32 +
                (k & 31)) = v;
    }
  }
}

// ---------------- K1: Q/K/V projections (tiled in, tiled out) ----------------
__global__ __launch_bounds__(256) void proj_all(
    const f16* __restrict__ WQt, const f16* __restrict__ WKt,
    const f16* __restrict__ WVt, const float* __restrict__ bq,
    const float* __restrict__ bk, const float* __restrict__ bv,
    const f16* __restrict__ xtt, f16* __restrict__ QTt, f16* __restrict__ KTt,
    f16* __restrict__ Vt) {
  // grid: (N/64, 6, B). y<2 -> q/k path; y>=2 -> v path with o0=(y-2)*64.
  int n0 = blockIdx.x * 64;
  int y = blockIdx.y;
  int b = blockIdx.z;
  int tid = threadIdx.x, lane = tid & 63, w = tid >> 6;
  int l15 = lane & 15, quad = lane >> 4;
  const f16* xtb = xtt + (size_t)b * N_ * C_;
  if (y < 2) {
    const f16* Wt = y ? WKt : WQt;
    const float* bias = y ? bk : bq;
    f16* outT = y ? KTt : QTt;
    f32x4 acc[4];
#pragma unroll
    for (int nt = 0; nt < 4; nt++) acc[nt] = (f32x4){0.f, 0.f, 0.f, 0.f};
#pragma unroll
    for (int kt = 0; kt < 8; kt++) {
      f16x8 a = *(const f16x8*)(Wt + ((size_t)w * 8 + kt) * TS + TILE_OFF(l15, quad));
#pragma unroll
      for (int nt = 0; nt < 4; nt++) {
        f16x8 bf = *(const f16x8*)(xtb + ((size_t)((n0 >> 4) + nt) * 8 + kt) * TS +
                                   TILE_OFF(l15, quad));
        acc[nt] = __builtin_amdgcn_mfma_f32_16x16x32_f16(a, bf, acc[nt], 0, 0, 0);
      }
    }
    // D rows o = 16w+4quad+r, cols n = n0+16nt+l15 -> A-tiles [n/16][2][16][32]
    f16* ob = outT + (size_t)b * N_ * CQK;
    int o_lo = 16 * (w & 1) + 4 * quad;
    int okt = w >> 1;
#pragma unroll
    for (int nt = 0; nt < 4; nt++) {
      f16x4 vals;
#pragma unroll
      for (int r = 0; r < 4; r++)
        vals[r] = (f16)(acc[nt][r] + bias[16 * w + 4 * quad + r]);
      *(f16x4*)(ob + ((size_t)((n0 >> 4) + nt) * 2 + okt) * TS + l15 * 32 + o_lo) =
          vals;
    }
  } else {
    int o0 = (y - 2) * 64;
    f32x4 acc[4];
#pragma unroll
    for (int ot = 0; ot < 4; ot++) acc[ot] = (f32x4){0.f, 0.f, 0.f, 0.f};
#pragma unroll
    for (int kt = 0; kt < 8; kt++) {
      f16x8 a = *(const f16x8*)(xtb + ((size_t)((n0 >> 4) + w) * 8 + kt) * TS +
                                TILE_OFF(l15, quad));
#pragma unroll
      for (int ot = 0; ot < 4; ot++) {
        f16x8 bb = *(const f16x8*)(WVt + ((size_t)((o0 >> 4) + ot) * 8 + kt) * TS +
                                   TILE_OFF(l15, quad));
        acc[ot] = __builtin_amdgcn_mfma_f32_16x16x32_f16(a, bb, acc[ot], 0, 0, 0);
      }
    }
    // D rows n = n0+16w+4quad+r, cols o = o0+16ot+l15 -> V A-tiles [c/16][128][16][32]
    f16* vbout = Vt + (size_t)b * C_ * N_;
    int n_lo = 16 * (w & 1) + 4 * quad;
    int ntile = (n0 >> 5) + (w >> 1);
#pragma unroll
    for (int ot = 0; ot < 4; ot++) {
      float bvv = bv[o0 + 16 * ot + l15];
      f16x4 vals;
#pragma unroll
      for (int r = 0; r < 4; r++) vals[r] = (f16)(acc[ot][r] + bvv);
      *(f16x4*)(vbout + ((size_t)((o0 >> 4) + ot) * 128 + ntile) * TS + l15 * 32 +
                n_lo) = vals;
    }
  }
}

// ---------------- K2: fused attention (tiled loads, swizzled P LDS) ----------
__global__ __launch_bounds__(256, 2) void attn(const f16* __restrict__ qt,
                                               const f16* __restrict__ kt,
                                               const f16* __restrict__ v,
                                               f16* __restrict__ oT) {
  // grid: (N/64 m-tiles, SEG, B); 4 waves.
  // P^T LDS: logical [64 m][256 B of n] (NB=128 f16 per row!), XOR-swizzled by
  // (row&7)<<4 -> write hits b64 4-cyc floor, read hits b128 8-cyc floor.
  __shared__ __align__(16) f16 sPt[2][64][128];  // 2 x 16 KB
  int m0 = blockIdx.x * 64;
  int seg = blockIdx.y;
  int b = blockIdx.z;
  int tid = threadIdx.x, lane = tid & 63, w = tid >> 6;
  int l15 = lane & 15, quad = lane >> 4;
  const f16* qtb = qt + (size_t)b * N_ * CQK;
  const f16* ktb = kt + (size_t)b * N_ * CQK;
  const f16* vb = v + (size_t)b * C_ * N_;

  f32x4 oacc[4][4];
#pragma unroll
  for (int ct = 0; ct < 4; ct++)
#pragma unroll
    for (int mt = 0; mt < 4; mt++) oacc[ct][mt] = (f32x4){0.f, 0.f, 0.f, 0.f};

  f16x8 kf[4][2];
#pragma unroll
  for (int mt = 0; mt < 4; mt++)
#pragma unroll
    for (int ks = 0; ks < 2; ks++)
      kf[mt][ks] = *(const f16x8*)(ktb + ((size_t)((m0 >> 4) + mt) * 2 + ks) * TS +
                                   TILE_OFF(l15, quad));

  f16x8 qf[2][2];
  {
    int nq = seg * SEGN;
#pragma unroll
    for (int nt = 0; nt < 2; nt++)
#pragma unroll
      for (int ks = 0; ks < 2; ks++)
        qf[nt][ks] = *(const f16x8*)(qtb +
                                     ((size_t)((nq >> 4) + 2 * w + nt) * 2 + ks) * TS +
                                     TILE_OFF(l15, quad));
  }

  for (int it = 0; it < ITERS; it++) {
    int n0 = seg * SEGN + it * NB;
    // V first half (n-tiles +0,+1), consumed after the barrier
    f16x8 vfA[2][4];
#pragma unroll
    for (int ks = 0; ks < 2; ks++)
#pragma unroll
      for (int ct = 0; ct < 4; ct++)
        vfA[ks][ct] = *(const f16x8*)(vb +
                                      ((size_t)(4 * w + ct) * 128 + (n0 >> 5) + ks) * TS +
                                      TILE_OFF(l15, quad));

    char* buf = (char*)sPt[it & 1];
#pragma unroll
    for (int nt = 0; nt < 2; nt++) {
      f32x4 sacc[4];
#pragma unroll
      for (int mt = 0; mt < 4; mt++) sacc[mt] = (f32x4){0.f, 0.f, 0.f, 0.f};
#pragma unroll
      for (int ks = 0; ks < 2; ks++)
#pragma unroll
        for (int mt = 0; mt < 4; mt++)
          sacc[mt] = __builtin_amdgcn_mfma_f32_16x16x32_f16(qf[nt][ks], kf[mt][ks],
                                                            sacc[mt], 0, 0, 0);
#pragma unroll
      for (int mt = 0; mt < 4; mt++) {
        f16x4 p;
#pragma unroll
        for (int r = 0; r < 4; r++) {
          float s = sacc[mt][r];
          p[r] = (f16)(s > 0.0f ? s : (__expf(s) - 1.0f));
        }
        int row = 16 * mt + l15;
        int colb = (64 * w + 32 * nt + 8 * quad) ^ ((row & 7) << 4);
        *(f16x4*)(buf + row * 256 + colb) = p;
      }
    }
    __syncthreads();

    // O phase
    f16x8 vfB[2][4];
    f16x8 pa[4];
#pragma unroll
    for (int mt = 0; mt < 4; mt++) {
      int row = 16 * mt + l15;
      int colb = (quad * 16) ^ ((row & 7) << 4);
      pa[mt] = *(const f16x8*)(buf + row * 256 + colb);
    }
#pragma unroll
    for (int ks = 0; ks < 2; ks++)
#pragma unroll
      for (int ct = 0; ct < 4; ct++)
        vfB[ks][ct] = *(const f16x8*)(vb + ((size_t)(4 * w + ct) * 128 + (n0 >> 5) +
                                            2 + ks) * TS +
                                      TILE_OFF(l15, quad));
#pragma unroll
    for (int ct = 0; ct < 4; ct++)
#pragma unroll
      for (int mt = 0; mt < 4; mt++)
        oacc[ct][mt] = __builtin_amdgcn_mfma_f32_16x16x32_f16(vfA[0][ct], pa[mt],
                                                              oacc[ct][mt], 0, 0, 0);
    if (it + 1 < ITERS) {
      int nq = n0 + NB;
#pragma unroll
      for (int nt = 0; nt < 2; nt++)
#pragma unroll
        for (int ks = 0; ks < 2; ks++)
          qf[nt][ks] = *(const f16x8*)(qtb +
                                       ((size_t)((nq >> 4) + 2 * w + nt) * 2 + ks) * TS +
                                       TILE_OFF(l15, quad));
    }
#pragma unroll
    for (int mt = 0; mt < 4; mt++) {
      int row = 16 * mt + l15;
      pa[mt] = *(const f16x8*)(buf + row * 256 + ((64 + quad * 16) ^ ((row & 7) << 4)));
    }
#pragma unroll
    for (int ct = 0; ct < 4; ct++)
#pragma unroll
      for (int mt = 0; mt < 4; mt++)
        oacc[ct][mt] = __builtin_amdgcn_mfma_f32_16x16x32_f16(vfA[1][ct], pa[mt],
                                                              oacc[ct][mt], 0, 0, 0);
#pragma unroll
    for (int mt = 0; mt < 4; mt++) {
      int row = 16 * mt + l15;
      pa[mt] = *(const f16x8*)(buf + row * 256 + ((128 + quad * 16) ^ ((row & 7) << 4)));
    }
#pragma unroll
    for (int ct = 0; ct < 4; ct++)
#pragma unroll
      for (int mt = 0; mt < 4; mt++)
        oacc[ct][mt] = __builtin_amdgcn_mfma_f32_16x16x32_f16(vfB[0][ct], pa[mt],
                                                              oacc[ct][mt], 0, 0, 0);
#pragma unroll
    for (int mt = 0; mt < 4; mt++) {
      int row = 16 * mt + l15;
      pa[mt] = *(const f16x8*)(buf + row * 256 + ((192 + quad * 16) ^ ((row & 7) << 4)));
    }
#pragma unroll
    for (int ct = 0; ct < 4; ct++)
#pragma unroll
      for (int mt = 0; mt < 4; mt++)
        oacc[ct][mt] = __builtin_amdgcn_mfma_f32_16x16x32_f16(vfB[1][ct], pa[mt],
                                                              oacc[ct][mt], 0, 0, 0);
  }

  // epilogue: OTt B-tiles [m/16][8][16][32] per (seg,b); D rows c=64w+16ct+4quad+r,
  // cols m = m0+16mt+l15.
  f16* ob = oT + ((size_t)seg * B_ + b) * N_ * C_;
#pragma unroll
  for (int ct = 0; ct < 4; ct++) {
#pragma unroll
    for (int mt = 0; mt < 4; mt++) {
      f16x4 vals;
#pragma unroll
      for (int r = 0; r < 4; r++)
        vals[r] = (f16)(oacc[ct][mt][r] * (1.0f / (float)N_));
      size_t tb = ((size_t)((m0 >> 4) + mt) * 8 + 2 * w + (ct >> 1)) * TS;
      *(f16x4*)(ob + tb + l15 * 32 + 16 * (ct & 1) + 4 * quad) = vals;
    }
  }
}

// ---------------- K3: out[b][o][m] = wg . (OT0+OT1) + bg ----------------
__global__ __launch_bounds__(256) void final_proj(const f16* __restrict__ WGt,
                                                  const float* __restrict__ bias,
                                                  const f16* __restrict__ ot,
                                                  float* __restrict__ out) {
  // grid: (N/64 m, C/64 o, B). All operand loads tiled/coalesced.
  int m0 = blockIdx.x * 64, o0 = blockIdx.y * 64, b = blockIdx.z;
  int tid = threadIdx.x, lane = tid & 63, w = tid >> 6;
  int l15 = lane & 15, quad = lane >> 4;
  const f16* otb0 = ot + (size_t)b * N_ * C_;
  const f16* otb1 = ot + ((size_t)B_ + b) * N_ * C_;
  f32x4 acc[4];
#pragma unroll
  for (int mt = 0; mt < 4; mt++) acc[mt] = (f32x4){0.f, 0.f, 0.f, 0.f};
#pragma unroll
  for (int kt = 0; kt < 8; kt++) {
    f16x8 a = *(const f16x8*)(WGt + ((size_t)((o0 >> 4) + w) * 8 + kt) * TS +
                              TILE_OFF(l15, quad));
#pragma unroll
    for (int mt = 0; mt < 4; mt++) {
      size_t off = ((size_t)((m0 >> 4) + mt) * 8 + kt) * TS + TILE_OFF(l15, quad);
      f16x8 b0 = *(const f16x8*)(otb0 + off);
      f16x8 b1 = *(const f16x8*)(otb1 + off);
      f16x8 bb = b0 + b1;
      acc[mt] = __builtin_amdgcn_mfma_f32_16x16x32_f16(a, bb, acc[mt], 0, 0, 0);
    }
  }
  float* outb = out + (size_t)b * C_ * N_;
  int ol = o0 + 16 * w + quad * 4;
#pragma unroll
  for (int mt = 0; mt < 4; mt++) {
    int m = m0 + 16 * mt + l15;
#pragma unroll
    for (int r = 0; r < 4; r++)
      outb[(size_t)(ol + r) * N_ + m] = acc[mt][r] + bias[ol + r];
  }
}

extern "C" void kernel_launch(void* const* d_in, const int* in_sizes, int n_in,
                              void* d_out, int out_size, void* d_ws, size_t ws_size,
                              hipStream_t stream) {
  const float* x = (const float*)d_in[0];
  const float* wq = (const float*)d_in[1];
  const float* bq = (const float*)d_in[2];
  const float* wk = (const float*)d_in[3];
  const float* bk = (const float*)d_in[4];
  const float* wv = (const float*)d_in[5];
  const float* bv = (const float*)d_in[6];
  const float* wg = (const float*)d_in[7];
  const float* bg = (const float*)d_in[8];
  float* out = (float*)d_out;

  char* ws = (char*)d_ws;
  // OTt: [SEG][B][N/16][8][16][32] f16, 16.8 MB. Seg0 aliases XTt (dead by attn).
  f16* OTt = (f16*)ws;
  f16* XTt = (f16*)ws;
  ws += (size_t)SEG * B_ * N_ * C_ * sizeof(f16);                  // 16.8 MB
  f16* QTt = (f16*)ws; ws += (size_t)B_ * N_ * CQK * sizeof(f16);  // 2.1 MB
  f16* KTt = (f16*)ws; ws += (size_t)B_ * N_ * CQK * sizeof(f16);  // 2.1 MB
  f16* Vt  = (f16*)ws; ws += (size_t)B_ * C_ * N_ * sizeof(f16);   // 8.4 MB
  f16* WQt = (f16*)ws; ws += (size_t)CQK * C_ * sizeof(f16);
  f16* WKt = (f16*)ws; ws += (size_t)CQK * C_ * sizeof(f16);
  f16* WVt = (f16*)ws; ws += (size_t)C_ * C_ * sizeof(f16);
  f16* WGt = (f16*)ws; ws += (size_t)C_ * C_ * sizeof(f16);

  prep<<<dim3(68, 4, 4), 256, 0, stream>>>(x, wq, wk, wv, wg, XTt, WQt, WKt, WVt, WGt);
  proj_all<<<dim3(N_ / 64, 6, B_), 256, 0, stream>>>(WQt, WKt, WVt, bq, bk, bv,
                                                     XTt, QTt, KTt, Vt);
  attn<<<dim3(N_ / 64, SEG, B_), 256, 0, stream>>>(QTt, KTt, Vt, OTt);
  final_proj<<<dim3(N_ / 64, C_ / 64, B_), 256, 0, stream>>>(WGt, bg, OTt, out);
}